// Round 1
// baseline (1789.679 us; speedup 1.0000x reference)
//
#include <hip/hip_runtime.h>
#include <hip/hip_bf16.h>
#include <math.h>

// Problem constants
#define BB 2
#define TT 512
#define DD 1024
#define HH 16
#define DH 64
#define EE 8
#define KK 2
#define FF 4096
#define NTOK 1024  // B*T

// ---------------- LayerNorm ----------------
__global__ __launch_bounds__(256) void ln_kernel(const float* __restrict__ x,
                                                 const float* __restrict__ s,
                                                 const float* __restrict__ b,
                                                 float* __restrict__ out) {
    int row = blockIdx.x;
    int tid = threadIdx.x;
    const float* xr = x + (size_t)row * DD;
    float sm = 0.f, sq = 0.f;
    for (int i = tid; i < DD; i += 256) {
        float v = xr[i];
        sm += v; sq += v * v;
    }
    #pragma unroll
    for (int o = 32; o; o >>= 1) {
        sm += __shfl_down(sm, o);
        sq += __shfl_down(sq, o);
    }
    __shared__ float r1[4], r2[4];
    if ((tid & 63) == 0) { r1[tid >> 6] = sm; r2[tid >> 6] = sq; }
    __syncthreads();
    float tot  = r1[0] + r1[1] + r1[2] + r1[3];
    float totq = r2[0] + r2[1] + r2[2] + r2[3];
    float mu  = tot * (1.f / DD);
    float var = totq * (1.f / DD) - mu * mu;
    float inv = rsqrtf(var + 1e-5f);
    for (int i = tid; i < DD; i += 256) {
        float v = xr[i];
        out[(size_t)row * DD + i] = (v - mu) * inv * s[i] + b[i];
    }
}

// ---------------- Generic tiled f32 GEMM: C = A@W + bias (+res) ----------------
// MODE 0: C = A@W + bias
// MODE 1: C = res + A@W + bias
template <int MODE>
__global__ __launch_bounds__(256) void gemm64(const float* __restrict__ A,
                                              const float* __restrict__ W,
                                              const float* __restrict__ bias,
                                              const float* __restrict__ res,
                                              float* __restrict__ C,
                                              int N, int K) {
    __shared__ float As[16][68];
    __shared__ float Ws[16][64];
    int tid = threadIdx.x;
    int tx = tid & 15, ty = tid >> 4;
    int n0 = blockIdx.x * 64, m0 = blockIdx.y * 64;
    int ar = tid >> 2;            // A row within tile (0..63)
    int ac = (tid & 3) << 2;      // A col (k) within tile
    int wr = tid >> 4;            // W row (k) within tile
    int wc = (tid & 15) << 2;     // W col within tile
    const float* Arow = A + (size_t)(m0 + ar) * K;
    float acc[4][4] = {};
    for (int k0 = 0; k0 < K; k0 += 16) {
        float4 a4 = *(const float4*)(Arow + k0 + ac);
        As[ac][ar] = a4.x; As[ac + 1][ar] = a4.y; As[ac + 2][ar] = a4.z; As[ac + 3][ar] = a4.w;
        float4 w4 = *(const float4*)(W + (size_t)(k0 + wr) * N + n0 + wc);
        *(float4*)&Ws[wr][wc] = w4;
        __syncthreads();
        #pragma unroll
        for (int kk = 0; kk < 16; kk++) {
            float4 a = *(float4*)&As[kk][ty << 2];
            float4 w = *(float4*)&Ws[kk][tx << 2];
            acc[0][0] += a.x * w.x; acc[0][1] += a.x * w.y; acc[0][2] += a.x * w.z; acc[0][3] += a.x * w.w;
            acc[1][0] += a.y * w.x; acc[1][1] += a.y * w.y; acc[1][2] += a.y * w.z; acc[1][3] += a.y * w.w;
            acc[2][0] += a.z * w.x; acc[2][1] += a.z * w.y; acc[2][2] += a.z * w.z; acc[2][3] += a.z * w.w;
            acc[3][0] += a.w * w.x; acc[3][1] += a.w * w.y; acc[3][2] += a.w * w.z; acc[3][3] += a.w * w.w;
        }
        __syncthreads();
    }
    #pragma unroll
    for (int i = 0; i < 4; i++) {
        int row = m0 + (ty << 2) + i;
        #pragma unroll
        for (int j = 0; j < 4; j++) {
            int col = n0 + (tx << 2) + j;
            float v = acc[i][j] + bias[col];
            if (MODE == 1) v += res[(size_t)row * N + col];
            C[(size_t)row * N + col] = v;
        }
    }
}

// ---------------- Attention: scores + rel bias + softmax (one block per (b,h,t)) ----------------
__global__ __launch_bounds__(256) void attn_kernel(const float* __restrict__ qkv,
                                                   const float* __restrict__ rel_bias,
                                                   float* __restrict__ attn) {
    int blk = blockIdx.x;              // b*H*T + h*T + t
    int t = blk & (TT - 1);
    int h = (blk >> 9) & (HH - 1);
    int b = blk >> 13;
    int tid = threadIdx.x;
    __shared__ float qrow[DH];
    __shared__ float sc[TT];
    __shared__ float red[4];
    if (tid < DH)
        qrow[tid] = qkv[((size_t)(b * TT + t) * 3 + 0) * DD + h * DH + tid];
    __syncthreads();
    float lmax = -1e30f;
    for (int s = tid; s < TT; s += 256) {
        const float* kr = qkv + ((size_t)(b * TT + s) * 3 + 1) * DD + h * DH;
        float dot = 0.f;
        #pragma unroll
        for (int d = 0; d < DH; d++) dot += qrow[d] * kr[d];
        float val = dot * 0.125f + rel_bias[h * (2 * TT - 1) + (s - t + TT - 1)];
        sc[s] = val;
        lmax = fmaxf(lmax, val);
    }
    #pragma unroll
    for (int o = 32; o; o >>= 1) lmax = fmaxf(lmax, __shfl_down(lmax, o));
    if ((tid & 63) == 0) red[tid >> 6] = lmax;
    __syncthreads();
    float m = fmaxf(fmaxf(red[0], red[1]), fmaxf(red[2], red[3]));
    __syncthreads();
    float lsum = 0.f;
    for (int s = tid; s < TT; s += 256) {
        float e = expf(sc[s] - m);
        sc[s] = e;
        lsum += e;
    }
    #pragma unroll
    for (int o = 32; o; o >>= 1) lsum += __shfl_down(lsum, o);
    if ((tid & 63) == 0) red[tid >> 6] = lsum;
    __syncthreads();
    float inv = 1.f / (red[0] + red[1] + red[2] + red[3]);
    for (int s = tid; s < TT; s += 256)
        attn[(size_t)blk * TT + s] = sc[s] * inv;
}

// ---------------- ctx = attn @ v (one block per (b,h,t)) ----------------
__global__ __launch_bounds__(256) void ctx_kernel(const float* __restrict__ attn,
                                                  const float* __restrict__ qkv,
                                                  float* __restrict__ ctx) {
    int blk = blockIdx.x;
    int t = blk & (TT - 1);
    int h = (blk >> 9) & (HH - 1);
    int b = blk >> 13;
    int d = threadIdx.x & 63;
    int sp = threadIdx.x >> 6;
    const float* arow = attn + (size_t)blk * TT;
    float acc = 0.f;
    for (int s = sp; s < TT; s += 4)
        acc += arow[s] * qkv[((size_t)(b * TT + s) * 3 + 2) * DD + h * DH + d];
    __shared__ float part[4][64];
    part[sp][d] = acc;
    __syncthreads();
    if (sp == 0)
        ctx[((size_t)(b * TT + t)) * DD + h * DH + d] =
            part[0][d] + part[1][d] + part[2][d] + part[3][d];
}

// ---------------- text projection: txt[b,n] = text_state[b,:] @ w_txt[:,n] + b_txt[n] ----------------
__global__ __launch_bounds__(256) void txt_kernel(const float* __restrict__ ts,
                                                  const float* __restrict__ w,
                                                  const float* __restrict__ bias,
                                                  float* __restrict__ out) {
    int gid = blockIdx.x * 256 + threadIdx.x;   // 0..B*D-1
    int b = gid >> 10;
    int n = gid & (DD - 1);
    float acc = 0.f;
    for (int d = 0; d < DD; d++) acc += ts[b * DD + d] * w[(size_t)d * DD + n];
    out[gid] = acc + bias[n];
}

// ---------------- router: probs, top-2 gates, expert counts ----------------
__global__ __launch_bounds__(256) void router_kernel(const float* __restrict__ h2,
                                                     const float* __restrict__ txt,
                                                     const float* __restrict__ w_r,
                                                     const float* __restrict__ b_r,
                                                     float* __restrict__ probs,
                                                     float* __restrict__ gates,
                                                     int* __restrict__ counts) {
    int row = blockIdx.x;       // token
    int b = row >> 9;
    int tid = threadIdx.x;
    float acc[EE] = {};
    for (int d = tid; d < DD; d += 256) {
        float r = h2[(size_t)row * DD + d] + txt[b * DD + d];
        #pragma unroll
        for (int e = 0; e < EE; e++) acc[e] += r * w_r[d * EE + e];
    }
    #pragma unroll
    for (int e = 0; e < EE; e++)
        #pragma unroll
        for (int o = 32; o; o >>= 1) acc[e] += __shfl_down(acc[e], o);
    __shared__ float lds[4][EE];
    int lane = tid & 63, w = tid >> 6;
    if (lane == 0)
        for (int e = 0; e < EE; e++) lds[w][e] = acc[e];
    __syncthreads();
    if (tid == 0) {
        float lg[EE], p[EE];
        float mx = -1e30f;
        for (int e = 0; e < EE; e++) {
            lg[e] = lds[0][e] + lds[1][e] + lds[2][e] + lds[3][e] + b_r[e];
            mx = fmaxf(mx, lg[e]);
        }
        float sum = 0.f;
        for (int e = 0; e < EE; e++) { p[e] = expf(lg[e] - mx); sum += p[e]; }
        float invs = 1.f / sum;
        for (int e = 0; e < EE; e++) { p[e] *= invs; probs[row * EE + e] = p[e]; }
        // top-2 (ties -> lower index, matching lax.top_k)
        int i1 = 0;
        for (int e = 1; e < EE; e++) if (p[e] > p[i1]) i1 = e;
        int i2 = (i1 == 0) ? 1 : 0;
        for (int e = 0; e < EE; e++) if (e != i1 && p[e] > p[i2]) i2 = e;
        float gs = p[i1] + p[i2];
        for (int e = 0; e < EE; e++) gates[row * EE + e] = 0.f;
        gates[row * EE + i1] = p[i1] / gs;
        gates[row * EE + i2] = p[i2] / gs;
        atomicAdd(&counts[i1], 1);
        atomicAdd(&counts[i2], 1);
    }
}

// ---------------- expert offsets (exclusive prefix sum over 8) ----------------
__global__ void offs_kernel(const int* __restrict__ counts, int* __restrict__ offs) {
    if (threadIdx.x == 0) {
        int acc = 0;
        for (int e = 0; e < EE; e++) { offs[e] = acc; acc += counts[e]; }
    }
}

// ---------------- scatter tokens into per-expert lists ----------------
__global__ __launch_bounds__(256) void scatter_kernel(const float* __restrict__ gates,
                                                      const int* __restrict__ offs,
                                                      int* __restrict__ fill,
                                                      int* __restrict__ pair_tok,
                                                      float* __restrict__ pair_gate) {
    int t = blockIdx.x * 256 + threadIdx.x;   // token
    if (t >= NTOK) return;
    for (int e = 0; e < EE; e++) {
        float g = gates[t * EE + e];
        if (g > 0.f) {
            int pos = offs[e] + atomicAdd(&fill[e], 1);
            pair_tok[pos] = t;
            pair_gate[pos] = g;
        }
    }
}

// ---------------- diag = mean(probs) over tokens ----------------
__global__ __launch_bounds__(256) void diag_kernel(const float* __restrict__ probs,
                                                   float* __restrict__ out) {
    int e = blockIdx.x;
    int tid = threadIdx.x;
    float s = 0.f;
    for (int t = tid; t < NTOK; t += 256) s += probs[t * EE + e];
    #pragma unroll
    for (int o = 32; o; o >>= 1) s += __shfl_down(s, o);
    __shared__ float red[4];
    if ((tid & 63) == 0) red[tid >> 6] = s;
    __syncthreads();
    if (tid == 0) out[e] = (red[0] + red[1] + red[2] + red[3]) * (1.f / NTOK);
}

// ---------------- MoE GEMM1: hid = gelu(h2[tok] @ w1[e] + b1[e]) ----------------
__global__ __launch_bounds__(256) void moe_gemm1(const float* __restrict__ h2,
                                                 const float* __restrict__ w1,
                                                 const float* __restrict__ b1,
                                                 const int* __restrict__ pair_tok,
                                                 const int* __restrict__ counts,
                                                 const int* __restrict__ offs,
                                                 float* __restrict__ hid) {
    int e = blockIdx.y >> 4;
    int tile = blockIdx.y & 15;
    int cnt = counts[e];
    int row0 = tile * 64;
    if (row0 >= cnt) return;
    int base = offs[e];
    const float* W = w1 + (size_t)e * DD * FF;
    __shared__ float As[16][68];
    __shared__ float Ws[16][64];
    int tid = threadIdx.x;
    int tx = tid & 15, ty = tid >> 4;
    int n0 = blockIdx.x * 64;
    int ar = tid >> 2;
    int ac = (tid & 3) << 2;
    int wr = tid >> 4;
    int wc = (tid & 15) << 2;
    int arow = row0 + ar;
    int tok = pair_tok[base + ((arow < cnt) ? arow : (cnt - 1))];
    const float* Arow = h2 + (size_t)tok * DD;
    float acc[4][4] = {};
    for (int k0 = 0; k0 < DD; k0 += 16) {
        float4 a4 = *(const float4*)(Arow + k0 + ac);
        As[ac][ar] = a4.x; As[ac + 1][ar] = a4.y; As[ac + 2][ar] = a4.z; As[ac + 3][ar] = a4.w;
        float4 w4 = *(const float4*)(W + (size_t)(k0 + wr) * FF + n0 + wc);
        *(float4*)&Ws[wr][wc] = w4;
        __syncthreads();
        #pragma unroll
        for (int kk = 0; kk < 16; kk++) {
            float4 a = *(float4*)&As[kk][ty << 2];
            float4 w = *(float4*)&Ws[kk][tx << 2];
            acc[0][0] += a.x * w.x; acc[0][1] += a.x * w.y; acc[0][2] += a.x * w.z; acc[0][3] += a.x * w.w;
            acc[1][0] += a.y * w.x; acc[1][1] += a.y * w.y; acc[1][2] += a.y * w.z; acc[1][3] += a.y * w.w;
            acc[2][0] += a.z * w.x; acc[2][1] += a.z * w.y; acc[2][2] += a.z * w.z; acc[2][3] += a.z * w.w;
            acc[3][0] += a.w * w.x; acc[3][1] += a.w * w.y; acc[3][2] += a.w * w.z; acc[3][3] += a.w * w.w;
        }
        __syncthreads();
    }
    #pragma unroll
    for (int i = 0; i < 4; i++) {
        int prow = row0 + (ty << 2) + i;
        if (prow >= cnt) break;
        size_t off = (size_t)(base + prow) * FF + n0 + (tx << 2);
        #pragma unroll
        for (int j = 0; j < 4; j++) {
            float v = acc[i][j] + b1[e * FF + n0 + (tx << 2) + j];
            float u = 0.7978845608028654f * (v + 0.044715f * v * v * v);
            hid[off + j] = 0.5f * v * (1.f + tanhf(u));
        }
    }
}

// ---------------- MoE GEMM2: y[tok] += gate * (hid @ w2[e] + b2[e]) ----------------
__global__ __launch_bounds__(256) void moe_gemm2(const float* __restrict__ hid,
                                                 const float* __restrict__ w2,
                                                 const float* __restrict__ b2,
                                                 const int* __restrict__ pair_tok,
                                                 const float* __restrict__ pair_gate,
                                                 const int* __restrict__ counts,
                                                 const int* __restrict__ offs,
                                                 float* __restrict__ y) {
    int e = blockIdx.y >> 4;
    int tile = blockIdx.y & 15;
    int cnt = counts[e];
    int row0 = tile * 64;
    if (row0 >= cnt) return;
    int base = offs[e];
    const float* W = w2 + (size_t)e * FF * DD;
    __shared__ float As[16][68];
    __shared__ float Ws[16][64];
    int tid = threadIdx.x;
    int tx = tid & 15, ty = tid >> 4;
    int n0 = blockIdx.x * 64;
    int ar = tid >> 2;
    int ac = (tid & 3) << 2;
    int wr = tid >> 4;
    int wc = (tid & 15) << 2;
    int arow = row0 + ar;
    int aprow = base + ((arow < cnt) ? arow : (cnt - 1));
    const float* Arow = hid + (size_t)aprow * FF;
    float acc[4][4] = {};
    for (int k0 = 0; k0 < FF; k0 += 16) {
        float4 a4 = *(const float4*)(Arow + k0 + ac);
        As[ac][ar] = a4.x; As[ac + 1][ar] = a4.y; As[ac + 2][ar] = a4.z; As[ac + 3][ar] = a4.w;
        float4 w4 = *(const float4*)(W + (size_t)(k0 + wr) * DD + n0 + wc);
        *(float4*)&Ws[wr][wc] = w4;
        __syncthreads();
        #pragma unroll
        for (int kk = 0; kk < 16; kk++) {
            float4 a = *(float4*)&As[kk][ty << 2];
            float4 w = *(float4*)&Ws[kk][tx << 2];
            acc[0][0] += a.x * w.x; acc[0][1] += a.x * w.y; acc[0][2] += a.x * w.z; acc[0][3] += a.x * w.w;
            acc[1][0] += a.y * w.x; acc[1][1] += a.y * w.y; acc[1][2] += a.y * w.z; acc[1][3] += a.y * w.w;
            acc[2][0] += a.z * w.x; acc[2][1] += a.z * w.y; acc[2][2] += a.z * w.z; acc[2][3] += a.z * w.w;
            acc[3][0] += a.w * w.x; acc[3][1] += a.w * w.y; acc[3][2] += a.w * w.z; acc[3][3] += a.w * w.w;
        }
        __syncthreads();
    }
    #pragma unroll
    for (int i = 0; i < 4; i++) {
        int prow = row0 + (ty << 2) + i;
        if (prow >= cnt) break;
        int tok = pair_tok[base + prow];
        float g = pair_gate[base + prow];
        #pragma unroll
        for (int j = 0; j < 4; j++) {
            int col = n0 + (tx << 2) + j;
            atomicAdd(&y[(size_t)tok * DD + col], g * (acc[i][j] + b2[e * DD + col]));
        }
    }
}

// ---------------- final residual add ----------------
__global__ __launch_bounds__(256) void add_kernel(float* __restrict__ out,
                                                  const float* __restrict__ y) {
    int i = blockIdx.x * 256 + threadIdx.x;
    float4* o = (float4*)out;
    const float4* yy = (const float4*)y;
    float4 a = o[i], b = yy[i];
    a.x += b.x; a.y += b.y; a.z += b.z; a.w += b.w;
    o[i] = a;
}

extern "C" void kernel_launch(void* const* d_in, const int* in_sizes, int n_in,
                              void* d_out, int out_size, void* d_ws, size_t ws_size,
                              hipStream_t stream) {
    const float* x          = (const float*)d_in[0];
    const float* text_state = (const float*)d_in[1];
    const float* ln1_s      = (const float*)d_in[2];
    const float* ln1_b      = (const float*)d_in[3];
    const float* w_qkv      = (const float*)d_in[4];
    const float* b_qkv      = (const float*)d_in[5];
    const float* w_o        = (const float*)d_in[6];
    const float* b_o        = (const float*)d_in[7];
    const float* rel_bias   = (const float*)d_in[8];
    const float* ln2_s      = (const float*)d_in[9];
    const float* ln2_b      = (const float*)d_in[10];
    const float* w_txt      = (const float*)d_in[11];
    const float* b_txt      = (const float*)d_in[12];
    const float* w_r        = (const float*)d_in[13];
    const float* b_r        = (const float*)d_in[14];
    const float* w1         = (const float*)d_in[15];
    const float* b1         = (const float*)d_in[16];
    const float* w2         = (const float*)d_in[17];
    const float* b2         = (const float*)d_in[18];

    float* out = (float*)d_out;                 // [NTOK*D] x, then [E] diag

    float* ws = (float*)d_ws;
    float* h      = ws;                         // 1,048,576
    float* qkvb   = ws + 1048576;               // 3,145,728
    float* attn   = ws + 4194304;               // 8,388,608  (reused as hid)
    float* ctx    = ws + 12582912;              // 1,048,576  (reused as y)
    float* h2     = ws + 13631488;              // 1,048,576
    float* txt    = ws + 14680064;              // 2,048
    float* probs  = ws + 14682112;              // 8,192
    float* gates  = ws + 14690304;              // 8,192
    float* pgate  = ws + 14698496;              // 2,048
    int*   itmp   = (int*)(ws + 14700544);
    int* pair_tok = itmp;                       // 2,048
    int* counts   = itmp + 2048;                // 8
    int* offs     = itmp + 2056;                // 8
    int* fill     = itmp + 2064;                // 8
    float* hid = attn;
    float* y   = ctx;

    // 1. LN1
    ln_kernel<<<NTOK, 256, 0, stream>>>(x, ln1_s, ln1_b, h);
    // 2. QKV GEMM
    gemm64<0><<<dim3(3 * DD / 64, NTOK / 64), 256, 0, stream>>>(h, w_qkv, b_qkv, nullptr, qkvb, 3 * DD, DD);
    // 3. scores + softmax
    attn_kernel<<<BB * HH * TT, 256, 0, stream>>>(qkvb, rel_bias, attn);
    // 4. ctx = attn @ v
    ctx_kernel<<<BB * HH * TT, 256, 0, stream>>>(attn, qkvb, ctx);
    // 5. x1 = x + ctx @ w_o + b_o  -> d_out
    gemm64<1><<<dim3(DD / 64, NTOK / 64), 256, 0, stream>>>(ctx, w_o, b_o, x, out, DD, DD);
    // 6. zero y (reuses ctx region) and count/fill scratch
    hipMemsetAsync(y, 0, (size_t)NTOK * DD * sizeof(float), stream);
    hipMemsetAsync(counts, 0, 24 * sizeof(int), stream);
    // 7. LN2
    ln_kernel<<<NTOK, 256, 0, stream>>>(out, ln2_s, ln2_b, h2);
    // 8. text projection
    txt_kernel<<<(BB * DD) / 256, 256, 0, stream>>>(text_state, w_txt, b_txt, txt);
    // 9. router probs / gates / counts
    router_kernel<<<NTOK, 256, 0, stream>>>(h2, txt, w_r, b_r, probs, gates, counts);
    // 10. offsets
    offs_kernel<<<1, 64, 0, stream>>>(counts, offs);
    // 11. scatter token lists
    scatter_kernel<<<NTOK / 256, 256, 0, stream>>>(gates, offs, fill, pair_tok, pgate);
    // 12. diag
    diag_kernel<<<EE, 256, 0, stream>>>(probs, out + (size_t)NTOK * DD);
    // 13. MoE GEMM1 (gelu fused)
    moe_gemm1<<<dim3(FF / 64, EE * 16), 256, 0, stream>>>(h2, w1, b1, pair_tok, counts, offs, hid);
    // 14. MoE GEMM2 (gated atomic accumulate)
    moe_gemm2<<<dim3(DD / 64, EE * 16), 256, 0, stream>>>(hid, w2, b2, pair_tok, pgate, counts, offs, y);
    // 15. final residual add
    add_kernel<<<(NTOK * DD / 4) / 256, 256, 0, stream>>>(out, y);
}

// Round 2
// 1034.580 us; speedup vs baseline: 1.7299x; 1.7299x over previous
//
#include <hip/hip_runtime.h>
#include <hip/hip_bf16.h>
#include <math.h>

// Problem constants
#define BB 2
#define TT 512
#define DD 1024
#define HH 16
#define DHH 64
#define EE 8
#define FF 4096
#define NTOK 1024
#define CAP 2560   // >= 2048 + 8*63 rounded up to 64

typedef __attribute__((ext_vector_type(4))) float f32x4;
typedef __attribute__((ext_vector_type(8))) short short8;

__device__ __forceinline__ short f2b(float f) {
    __hip_bfloat16 h = __float2bfloat16(f);
    return *reinterpret_cast<short*>(&h);
}

// ---------------- LayerNorm (templated output dtype) ----------------
template <int BF>
__global__ __launch_bounds__(256) void ln_kernel(const float* __restrict__ x,
                                                 const float* __restrict__ s,
                                                 const float* __restrict__ b,
                                                 void* __restrict__ outp) {
    int row = blockIdx.x;
    int tid = threadIdx.x;
    const float* xr = x + (size_t)row * DD;
    float sm = 0.f, sq = 0.f;
    for (int i = tid; i < DD; i += 256) {
        float v = xr[i];
        sm += v; sq += v * v;
    }
    #pragma unroll
    for (int o = 32; o; o >>= 1) {
        sm += __shfl_down(sm, o);
        sq += __shfl_down(sq, o);
    }
    __shared__ float r1[4], r2[4];
    if ((tid & 63) == 0) { r1[tid >> 6] = sm; r2[tid >> 6] = sq; }
    __syncthreads();
    float tot  = r1[0] + r1[1] + r1[2] + r1[3];
    float totq = r2[0] + r2[1] + r2[2] + r2[3];
    float mu  = tot * (1.f / DD);
    float var = totq * (1.f / DD) - mu * mu;
    float inv = rsqrtf(var + 1e-5f);
    for (int i = tid; i < DD; i += 256) {
        float v = (xr[i] - mu) * inv * s[i] + b[i];
        if (BF) ((short*)outp)[(size_t)row * DD + i] = f2b(v);
        else    ((float*)outp)[(size_t)row * DD + i] = v;
    }
}

// ---------------- Transpose + cast f32 [K][N] -> bf16 [N][K] ----------------
__global__ __launch_bounds__(256) void transpose_cast(const float* __restrict__ src,
                                                      short* __restrict__ dst,
                                                      int K, int N) {
    __shared__ float t[32][33];
    src += (size_t)blockIdx.z * K * N;
    dst += (size_t)blockIdx.z * K * N;
    int k0 = blockIdx.y * 32, n0 = blockIdx.x * 32;
    int tx = threadIdx.x & 31, ty = threadIdx.x >> 5;   // 8 rows per pass
    #pragma unroll
    for (int p = 0; p < 4; p++) {
        int k = k0 + ty + p * 8;
        t[ty + p * 8][tx] = src[(size_t)k * N + n0 + tx];
    }
    __syncthreads();
    #pragma unroll
    for (int p = 0; p < 4; p++) {
        int n = n0 + ty + p * 8;
        dst[(size_t)n * K + k0 + tx] = f2b(t[tx][ty + p * 8]);
    }
}

// ---------------- Core bf16 MFMA GEMM loop (64x64 tile, BK=64, 4 waves) ----------------
// A: [M][K] bf16 row-major, B: [N][K] bf16 row-major (i.e. weight pre-transposed).
// LDS tiles hold 64 rows x 64 k, 16B-slot XOR-swizzled by (row&7).
__device__ __forceinline__ void gemm_loop(const short* __restrict__ A,
                                          const short* __restrict__ B,
                                          int K, short* As, short* Bs,
                                          f32x4 acc[2][2], int m0, int n0, int tid) {
    int wave = tid >> 6, lane = tid & 63;
    int wr = wave >> 1, wc = wave & 1;
    int lrow = lane & 15, lk = lane >> 4;
    int sr = tid >> 3, ss = tid & 7;
    int swz = ss ^ (sr & 7);
    for (int k0 = 0; k0 < K; k0 += 64) {
        uint4 v0 = ((const uint4*)(A + (size_t)(m0 + sr) * K + k0))[ss];
        uint4 v1 = ((const uint4*)(A + (size_t)(m0 + sr + 32) * K + k0))[ss];
        uint4 w0 = ((const uint4*)(B + (size_t)(n0 + sr) * K + k0))[ss];
        uint4 w1 = ((const uint4*)(B + (size_t)(n0 + sr + 32) * K + k0))[ss];
        ((uint4*)As)[sr * 8 + swz]        = v0;
        ((uint4*)As)[(sr + 32) * 8 + swz] = v1;
        ((uint4*)Bs)[sr * 8 + swz]        = w0;
        ((uint4*)Bs)[(sr + 32) * 8 + swz] = w1;
        __syncthreads();
        #pragma unroll
        for (int kk = 0; kk < 2; kk++) {
            int slot = kk * 4 + lk;
            short8 a[2], b[2];
            #pragma unroll
            for (int i = 0; i < 2; i++) {
                int row = wr * 32 + i * 16 + lrow;
                uint4 v = ((const uint4*)As)[row * 8 + (slot ^ (row & 7))];
                a[i] = *(short8*)&v;
            }
            #pragma unroll
            for (int j = 0; j < 2; j++) {
                int row = wc * 32 + j * 16 + lrow;
                uint4 v = ((const uint4*)Bs)[row * 8 + (slot ^ (row & 7))];
                b[j] = *(short8*)&v;
            }
            #pragma unroll
            for (int i = 0; i < 2; i++)
                #pragma unroll
                for (int j = 0; j < 2; j++)
                    acc[i][j] = __builtin_amdgcn_mfma_f32_16x16x32_bf16(a[i], b[j], acc[i][j], 0, 0, 0);
        }
        __syncthreads();
    }
}

// ---------------- Generic MFMA GEMM: MODE 0: C=A@W^T+bias ; MODE 1: C=res+A@W^T+bias ----------------
template <int MODE>
__global__ __launch_bounds__(256) void gemm_mfma(const short* __restrict__ A,
                                                 const short* __restrict__ Bw,
                                                 const float* __restrict__ bias,
                                                 const float* __restrict__ res,
                                                 float* __restrict__ C,
                                                 int N, int K) {
    __shared__ short As[64 * 64];
    __shared__ short Bs[64 * 64];
    int tid = threadIdx.x;
    int m0 = blockIdx.y * 64, n0 = blockIdx.x * 64;
    f32x4 acc[2][2] = {};
    gemm_loop(A, Bw, K, As, Bs, acc, m0, n0, tid);
    int wave = tid >> 6, lane = tid & 63;
    int wr = wave >> 1, wc = wave & 1;
    int lrow = lane & 15, lk = lane >> 4;
    #pragma unroll
    for (int i = 0; i < 2; i++) {
        #pragma unroll
        for (int j = 0; j < 2; j++) {
            int col = n0 + wc * 32 + j * 16 + lrow;
            float bv = bias[col];
            #pragma unroll
            for (int r = 0; r < 4; r++) {
                int row = m0 + wr * 32 + i * 16 + lk * 4 + r;
                float v = acc[i][j][r] + bv;
                if (MODE == 1) v += res[(size_t)row * N + col];
                C[(size_t)row * N + col] = v;
            }
        }
    }
}

// ---------------- MoE GEMM1: hid = gelu(Ag @ w1t[e]^T + b1[e]) (bf16 out) ----------------
__global__ __launch_bounds__(256) void moe_gemm1_mfma(const short* __restrict__ Ag,
                                                      const short* __restrict__ W1t,
                                                      const float* __restrict__ b1,
                                                      const int* __restrict__ counts,
                                                      const int* __restrict__ offs,
                                                      short* __restrict__ hid) {
    int e = blockIdx.y >> 4, tile = blockIdx.y & 15;
    int cnt = counts[e];
    int pcnt = (cnt + 63) & ~63;
    int row0 = tile * 64;
    if (row0 >= pcnt) return;
    int base = offs[e];
    const short* A  = Ag + (size_t)base * DD;
    const short* Bw = W1t + (size_t)e * FF * DD;   // [F][D]
    __shared__ short As[64 * 64];
    __shared__ short Bs[64 * 64];
    int tid = threadIdx.x;
    int n0 = blockIdx.x * 64;
    f32x4 acc[2][2] = {};
    gemm_loop(A, Bw, DD, As, Bs, acc, row0, n0, tid);
    int wave = tid >> 6, lane = tid & 63;
    int wr = wave >> 1, wc = wave & 1;
    int lrow = lane & 15, lk = lane >> 4;
    #pragma unroll
    for (int i = 0; i < 2; i++) {
        #pragma unroll
        for (int j = 0; j < 2; j++) {
            int col = n0 + wc * 32 + j * 16 + lrow;
            float bv = b1[e * FF + col];
            #pragma unroll
            for (int r = 0; r < 4; r++) {
                int row = row0 + wr * 32 + i * 16 + lk * 4 + r;
                float v = acc[i][j][r] + bv;
                float u = 0.7978845608028654f * (v + 0.044715f * v * v * v);
                float g = 0.5f * v * (1.f + tanhf(u));
                hid[(size_t)(base + row) * FF + col] = f2b(g);
            }
        }
    }
}

// ---------------- MoE GEMM2: pair_out = gate * (hid @ w2t[e]^T + b2[e]) ----------------
__global__ __launch_bounds__(256) void moe_gemm2_mfma(const short* __restrict__ hid,
                                                      const short* __restrict__ W2t,
                                                      const float* __restrict__ b2,
                                                      const float* __restrict__ pair_gate,
                                                      const int* __restrict__ counts,
                                                      const int* __restrict__ offs,
                                                      float* __restrict__ pair_out) {
    int e = blockIdx.y >> 4, tile = blockIdx.y & 15;
    int cnt = counts[e];
    int pcnt = (cnt + 63) & ~63;
    int row0 = tile * 64;
    if (row0 >= pcnt) return;
    int base = offs[e];
    const short* A  = hid + (size_t)base * FF;
    const short* Bw = W2t + (size_t)e * DD * FF;   // [D][F]
    __shared__ short As[64 * 64];
    __shared__ short Bs[64 * 64];
    int tid = threadIdx.x;
    int n0 = blockIdx.x * 64;
    f32x4 acc[2][2] = {};
    gemm_loop(A, Bw, FF, As, Bs, acc, row0, n0, tid);
    int wave = tid >> 6, lane = tid & 63;
    int wr = wave >> 1, wc = wave & 1;
    int lrow = lane & 15, lk = lane >> 4;
    #pragma unroll
    for (int i = 0; i < 2; i++) {
        #pragma unroll
        for (int j = 0; j < 2; j++) {
            int col = n0 + wc * 32 + j * 16 + lrow;
            float bv = b2[e * DD + col];
            #pragma unroll
            for (int r = 0; r < 4; r++) {
                int row = row0 + wr * 32 + i * 16 + lk * 4 + r;
                float g = pair_gate[base + row];
                pair_out[(size_t)(base + row) * DD + col] = g * (acc[i][j][r] + bv);
            }
        }
    }
}

// ---------------- Attention: scores + rel bias + softmax ----------------
__global__ __launch_bounds__(256) void attn_kernel(const float* __restrict__ qkv,
                                                   const float* __restrict__ rel_bias,
                                                   float* __restrict__ attn) {
    int blk = blockIdx.x;              // b*H*T + h*T + t
    int t = blk & (TT - 1);
    int h = (blk >> 9) & (HH - 1);
    int b = blk >> 13;
    int tid = threadIdx.x;
    __shared__ float qrow[DHH];
    __shared__ float sc[TT];
    __shared__ float red[4];
    if (tid < DHH)
        qrow[tid] = qkv[((size_t)(b * TT + t) * 3 + 0) * DD + h * DHH + tid];
    __syncthreads();
    float lmax = -1e30f;
    for (int s = tid; s < TT; s += 256) {
        const float* kr = qkv + ((size_t)(b * TT + s) * 3 + 1) * DD + h * DHH;
        float dot = 0.f;
        #pragma unroll
        for (int d = 0; d < DHH; d++) dot += qrow[d] * kr[d];
        float val = dot * 0.125f + rel_bias[h * (2 * TT - 1) + (s - t + TT - 1)];
        sc[s] = val;
        lmax = fmaxf(lmax, val);
    }
    #pragma unroll
    for (int o = 32; o; o >>= 1) lmax = fmaxf(lmax, __shfl_down(lmax, o));
    if ((tid & 63) == 0) red[tid >> 6] = lmax;
    __syncthreads();
    float m = fmaxf(fmaxf(red[0], red[1]), fmaxf(red[2], red[3]));
    __syncthreads();
    float lsum = 0.f;
    for (int s = tid; s < TT; s += 256) {
        float e = expf(sc[s] - m);
        sc[s] = e;
        lsum += e;
    }
    #pragma unroll
    for (int o = 32; o; o >>= 1) lsum += __shfl_down(lsum, o);
    if ((tid & 63) == 0) red[tid >> 6] = lsum;
    __syncthreads();
    float inv = 1.f / (red[0] + red[1] + red[2] + red[3]);
    for (int s = tid; s < TT; s += 256)
        attn[(size_t)blk * TT + s] = sc[s] * inv;
}

// ---------------- ctx = attn @ v (bf16 out) ----------------
__global__ __launch_bounds__(256) void ctx_kernel(const float* __restrict__ attn,
                                                  const float* __restrict__ qkv,
                                                  short* __restrict__ ctx) {
    int blk = blockIdx.x;
    int t = blk & (TT - 1);
    int h = (blk >> 9) & (HH - 1);
    int b = blk >> 13;
    int d = threadIdx.x & 63;
    int sp = threadIdx.x >> 6;
    const float* arow = attn + (size_t)blk * TT;
    float acc = 0.f;
    for (int s = sp; s < TT; s += 4)
        acc += arow[s] * qkv[((size_t)(b * TT + s) * 3 + 2) * DD + h * DHH + d];
    __shared__ float part[4][64];
    part[sp][d] = acc;
    __syncthreads();
    if (sp == 0)
        ctx[((size_t)(b * TT + t)) * DD + h * DHH + d] =
            f2b(part[0][d] + part[1][d] + part[2][d] + part[3][d]);
}

// ---------------- text projection ----------------
__global__ __launch_bounds__(256) void txt_kernel(const float* __restrict__ ts,
                                                  const float* __restrict__ w,
                                                  const float* __restrict__ bias,
                                                  float* __restrict__ out) {
    int gid = blockIdx.x * 256 + threadIdx.x;   // 0..B*D-1
    int b = gid >> 10;
    int n = gid & (DD - 1);
    float acc = 0.f;
    for (int d = 0; d < DD; d++) acc += ts[b * DD + d] * w[(size_t)d * DD + n];
    out[gid] = acc + bias[n];
}

// ---------------- router ----------------
__global__ __launch_bounds__(256) void router_kernel(const float* __restrict__ h2,
                                                     const float* __restrict__ txt,
                                                     const float* __restrict__ w_r,
                                                     const float* __restrict__ b_r,
                                                     float* __restrict__ probs,
                                                     float* __restrict__ gates,
                                                     int* __restrict__ counts) {
    int row = blockIdx.x;       // token
    int b = row >> 9;
    int tid = threadIdx.x;
    float acc[EE] = {};
    for (int d = tid; d < DD; d += 256) {
        float r = h2[(size_t)row * DD + d] + txt[b * DD + d];
        #pragma unroll
        for (int e = 0; e < EE; e++) acc[e] += r * w_r[d * EE + e];
    }
    #pragma unroll
    for (int e = 0; e < EE; e++)
        #pragma unroll
        for (int o = 32; o; o >>= 1) acc[e] += __shfl_down(acc[e], o);
    __shared__ float lds[4][EE];
    int lane = tid & 63, w = tid >> 6;
    if (lane == 0)
        for (int e = 0; e < EE; e++) lds[w][e] = acc[e];
    __syncthreads();
    if (tid == 0) {
        float lg[EE], p[EE];
        float mx = -1e30f;
        for (int e = 0; e < EE; e++) {
            lg[e] = lds[0][e] + lds[1][e] + lds[2][e] + lds[3][e] + b_r[e];
            mx = fmaxf(mx, lg[e]);
        }
        float sum = 0.f;
        for (int e = 0; e < EE; e++) { p[e] = expf(lg[e] - mx); sum += p[e]; }
        float invs = 1.f / sum;
        for (int e = 0; e < EE; e++) { p[e] *= invs; probs[row * EE + e] = p[e]; }
        int i1 = 0;
        for (int e = 1; e < EE; e++) if (p[e] > p[i1]) i1 = e;
        int i2 = (i1 == 0) ? 1 : 0;
        for (int e = 0; e < EE; e++) if (e != i1 && p[e] > p[i2]) i2 = e;
        float gs = p[i1] + p[i2];
        for (int e = 0; e < EE; e++) gates[row * EE + e] = 0.f;
        gates[row * EE + i1] = p[i1] / gs;
        gates[row * EE + i2] = p[i2] / gs;
        atomicAdd(&counts[i1], 1);
        atomicAdd(&counts[i2], 1);
    }
}

// ---------------- expert offsets (64-aligned segments) ----------------
__global__ void offs_kernel(const int* __restrict__ counts, int* __restrict__ offs) {
    if (threadIdx.x == 0) {
        int acc = 0;
        for (int e = 0; e < EE; e++) { offs[e] = acc; acc += (counts[e] + 63) & ~63; }
    }
}

// ---------------- scatter tokens into per-expert lists ----------------
__global__ __launch_bounds__(256) void scatter_kernel(const float* __restrict__ gates,
                                                      const int* __restrict__ offs,
                                                      int* __restrict__ fill,
                                                      int* __restrict__ tok_pos,
                                                      float* __restrict__ pair_gate) {
    int t = blockIdx.x * 256 + threadIdx.x;   // token
    if (t >= NTOK) return;
    int slot = 0;
    for (int e = 0; e < EE; e++) {
        float g = gates[t * EE + e];
        if (g > 0.f) {
            int pos = offs[e] + atomicAdd(&fill[e], 1);
            tok_pos[t * 2 + slot] = pos;
            pair_gate[pos] = g;
            slot++;
        }
    }
}

// ---------------- gather tokens (h2 f32 -> bf16 rows of Ag) ----------------
__global__ __launch_bounds__(256) void gather_tokens(const float* __restrict__ h2,
                                                     const int* __restrict__ tok_pos,
                                                     short* __restrict__ Ag) {
    int i = blockIdx.x;          // 0..2047  (t = i>>1)
    int pos = tok_pos[i];
    int t = i >> 1;
    int d = threadIdx.x * 4;
    #pragma unroll
    for (int k = 0; k < 4; k++)
        Ag[(size_t)pos * DD + d + k] = f2b(h2[(size_t)t * DD + d + k]);
}

// ---------------- diag = mean(probs) ----------------
__global__ __launch_bounds__(256) void diag_kernel(const float* __restrict__ probs,
                                                   float* __restrict__ out) {
    int e = blockIdx.x;
    int tid = threadIdx.x;
    float s = 0.f;
    for (int t = tid; t < NTOK; t += 256) s += probs[t * EE + e];
    #pragma unroll
    for (int o = 32; o; o >>= 1) s += __shfl_down(s, o);
    __shared__ float red[4];
    if ((tid & 63) == 0) red[tid >> 6] = s;
    __syncthreads();
    if (tid == 0) out[e] = (red[0] + red[1] + red[2] + red[3]) * (1.f / NTOK);
}

// ---------------- final: out += pair_out[posA] + pair_out[posB] ----------------
__global__ __launch_bounds__(256) void finaladd_kernel(float* __restrict__ out,
                                                       const float* __restrict__ pair_out,
                                                       const int* __restrict__ tok_pos) {
    int t = blockIdx.x;
    int pA = tok_pos[2 * t], pB = tok_pos[2 * t + 1];
    int d = threadIdx.x * 4;
    float4 a = *(const float4*)&out[(size_t)t * DD + d];
    float4 u = *(const float4*)&pair_out[(size_t)pA * DD + d];
    float4 v = *(const float4*)&pair_out[(size_t)pB * DD + d];
    a.x += u.x + v.x; a.y += u.y + v.y; a.z += u.z + v.z; a.w += u.w + v.w;
    *(float4*)&out[(size_t)t * DD + d] = a;
}

extern "C" void kernel_launch(void* const* d_in, const int* in_sizes, int n_in,
                              void* d_out, int out_size, void* d_ws, size_t ws_size,
                              hipStream_t stream) {
    const float* x          = (const float*)d_in[0];
    const float* text_state = (const float*)d_in[1];
    const float* ln1_s      = (const float*)d_in[2];
    const float* ln1_b      = (const float*)d_in[3];
    const float* w_qkv      = (const float*)d_in[4];
    const float* b_qkv      = (const float*)d_in[5];
    const float* w_o        = (const float*)d_in[6];
    const float* b_o        = (const float*)d_in[7];
    const float* rel_bias   = (const float*)d_in[8];
    const float* ln2_s      = (const float*)d_in[9];
    const float* ln2_b      = (const float*)d_in[10];
    const float* w_txt      = (const float*)d_in[11];
    const float* b_txt      = (const float*)d_in[12];
    const float* w_r        = (const float*)d_in[13];
    const float* b_r        = (const float*)d_in[14];
    const float* w1         = (const float*)d_in[15];
    const float* b1         = (const float*)d_in[16];
    const float* w2         = (const float*)d_in[17];
    const float* b2         = (const float*)d_in[18];

    float* out = (float*)d_out;   // [NTOK*D] then [E] diag

    // ---- workspace layout (bytes) ----
    char* p = (char*)d_ws;
    auto alloc = [&](size_t bytes) { char* r = p; p += (bytes + 255) & ~(size_t)255; return r; };
    short* h1b      = (short*)alloc((size_t)NTOK * DD * 2);          // LN1 out bf16
    float* qkv      = (float*)alloc((size_t)NTOK * 3 * DD * 4);      // f32
    float* attnp    = (float*)alloc((size_t)BB * HH * TT * TT * 4);  // 33.5 MB
    short* ctxb     = (short*)alloc((size_t)NTOK * DD * 2);          // bf16
    float* h2       = (float*)alloc((size_t)NTOK * DD * 4);
    float* txt      = (float*)alloc((size_t)BB * DD * 4);
    float* probs    = (float*)alloc((size_t)NTOK * EE * 4);
    float* gates    = (float*)alloc((size_t)NTOK * EE * 4);
    short* Ag       = (short*)alloc((size_t)CAP * DD * 2);
    short* hid      = (short*)alloc((size_t)CAP * FF * 2);
    float* pair_out = (float*)alloc((size_t)CAP * DD * 4);
    float* pair_gate= (float*)alloc((size_t)CAP * 4);
    int*   counts   = (int*)alloc(8 * 4);
    int*   fill     = (int*)alloc(8 * 4);
    int*   offs     = (int*)alloc(8 * 4);
    int*   tok_pos  = (int*)alloc((size_t)NTOK * 2 * 4);
    short* wqkvT    = (short*)alloc((size_t)3 * DD * DD * 2);        // [3D][D]
    short* woT      = (short*)alloc((size_t)DD * DD * 2);            // [D][D]
    short* w1T      = (short*)alloc((size_t)EE * FF * DD * 2);       // [E][F][D]
    short* w2T      = (short*)alloc((size_t)EE * DD * FF * 2);       // [E][D][F]

    // ---- weight prep: transpose + cast to bf16 [N][K] ----
    transpose_cast<<<dim3(3 * DD / 32, DD / 32, 1), 256, 0, stream>>>(w_qkv, wqkvT, DD, 3 * DD);
    transpose_cast<<<dim3(DD / 32, DD / 32, 1), 256, 0, stream>>>(w_o, woT, DD, DD);
    transpose_cast<<<dim3(FF / 32, DD / 32, EE), 256, 0, stream>>>(w1, w1T, DD, FF);
    transpose_cast<<<dim3(DD / 32, FF / 32, EE), 256, 0, stream>>>(w2, w2T, FF, DD);

    // ---- 1. LN1 (bf16 out) ----
    ln_kernel<1><<<NTOK, 256, 0, stream>>>(x, ln1_s, ln1_b, h1b);
    // ---- 2. QKV GEMM (MFMA) ----
    gemm_mfma<0><<<dim3(3 * DD / 64, NTOK / 64), 256, 0, stream>>>(h1b, wqkvT, b_qkv, nullptr, qkv, 3 * DD, DD);
    // ---- 3. scores + softmax ----
    attn_kernel<<<BB * HH * TT, 256, 0, stream>>>(qkv, rel_bias, attnp);
    // ---- 4. ctx = attn @ v (bf16 out) ----
    ctx_kernel<<<BB * HH * TT, 256, 0, stream>>>(attnp, qkv, ctxb);
    // ---- 5. x1 = x + ctx @ w_o + b_o -> out (MFMA) ----
    gemm_mfma<1><<<dim3(DD / 64, NTOK / 64), 256, 0, stream>>>(ctxb, woT, b_o, x, out, DD, DD);
    // ---- 6. LN2 (f32 out) ----
    ln_kernel<0><<<NTOK, 256, 0, stream>>>(out, ln2_s, ln2_b, h2);
    // ---- 7. text projection ----
    txt_kernel<<<(BB * DD) / 256, 256, 0, stream>>>(text_state, w_txt, b_txt, txt);
    // ---- 8. zero scratch ----
    hipMemsetAsync(counts, 0, 8 * 4, stream);
    hipMemsetAsync(fill, 0, 8 * 4, stream);
    hipMemsetAsync(Ag, 0, (size_t)CAP * DD * 2, stream);
    // ---- 9. router ----
    router_kernel<<<NTOK, 256, 0, stream>>>(h2, txt, w_r, b_r, probs, gates, counts);
    // ---- 10. aligned offsets ----
    offs_kernel<<<1, 64, 0, stream>>>(counts, offs);
    // ---- 11. scatter ----
    scatter_kernel<<<NTOK / 256, 256, 0, stream>>>(gates, offs, fill, tok_pos, pair_gate);
    // ---- 12. gather rows into Ag (bf16) ----
    gather_tokens<<<NTOK * 2, 256, 0, stream>>>(h2, tok_pos, Ag);
    // ---- 13. diag ----
    diag_kernel<<<EE, 256, 0, stream>>>(probs, out + (size_t)NTOK * DD);
    // ---- 14. MoE GEMM1 (MFMA + gelu, bf16 out) ----
    moe_gemm1_mfma<<<dim3(FF / 64, EE * 16), 256, 0, stream>>>(Ag, w1T, b1, counts, offs, hid);
    // ---- 15. MoE GEMM2 (MFMA, gated) ----
    moe_gemm2_mfma<<<dim3(DD / 64, EE * 16), 256, 0, stream>>>(hid, w2T, b2, pair_gate, counts, offs, pair_out);
    // ---- 16. final add ----
    finaladd_kernel<<<NTOK, 256, 0, stream>>>(out, pair_out, tok_pos);
}

// Round 3
// 415.208 us; speedup vs baseline: 4.3103x; 2.4917x over previous
//
#include <hip/hip_runtime.h>
#include <hip/hip_bf16.h>
#include <math.h>

// Problem constants
#define BB 2
#define TT 512
#define DD 1024
#define HH 16
#define DHH 64
#define EE 8
#define FF 4096
#define NTOK 1024
#define CAP 2560   // >= 2048 + 8*63 rounded up to 64

typedef __attribute__((ext_vector_type(4))) float f32x4;
typedef __attribute__((ext_vector_type(8))) short short8;

__device__ __forceinline__ short f2b(float f) {
    __hip_bfloat16 h = __float2bfloat16(f);
    return *reinterpret_cast<short*>(&h);
}

// async global->LDS, 16B per lane. LDS dest = wave-uniform base + lane*16.
__device__ __forceinline__ void gload16(const short* g, short* l) {
    __builtin_amdgcn_global_load_lds((const __attribute__((address_space(1))) unsigned int*)g,
                                     (__attribute__((address_space(3))) unsigned int*)l,
                                     16, 0, 0);
}

// ---------------- LayerNorm (templated output dtype) ----------------
template <int BF>
__global__ __launch_bounds__(256) void ln_kernel(const float* __restrict__ x,
                                                 const float* __restrict__ s,
                                                 const float* __restrict__ b,
                                                 void* __restrict__ outp) {
    int row = blockIdx.x;
    int tid = threadIdx.x;
    const float* xr = x + (size_t)row * DD;
    float sm = 0.f, sq = 0.f;
    for (int i = tid; i < DD; i += 256) {
        float v = xr[i];
        sm += v; sq += v * v;
    }
    #pragma unroll
    for (int o = 32; o; o >>= 1) {
        sm += __shfl_down(sm, o);
        sq += __shfl_down(sq, o);
    }
    __shared__ float r1[4], r2[4];
    if ((tid & 63) == 0) { r1[tid >> 6] = sm; r2[tid >> 6] = sq; }
    __syncthreads();
    float tot  = r1[0] + r1[1] + r1[2] + r1[3];
    float totq = r2[0] + r2[1] + r2[2] + r2[3];
    float mu  = tot * (1.f / DD);
    float var = totq * (1.f / DD) - mu * mu;
    float inv = rsqrtf(var + 1e-5f);
    for (int i = tid; i < DD; i += 256) {
        float v = (xr[i] - mu) * inv * s[i] + b[i];
        if (BF) ((short*)outp)[(size_t)row * DD + i] = f2b(v);
        else    ((float*)outp)[(size_t)row * DD + i] = v;
    }
}

// ---------------- Transpose + cast f32 [K][N] -> bf16 [N][K] ----------------
__global__ __launch_bounds__(256) void transpose_cast(const float* __restrict__ src,
                                                      short* __restrict__ dst,
                                                      int K, int N) {
    __shared__ float t[32][33];
    src += (size_t)blockIdx.z * K * N;
    dst += (size_t)blockIdx.z * K * N;
    int k0 = blockIdx.y * 32, n0 = blockIdx.x * 32;
    int tx = threadIdx.x & 31, ty = threadIdx.x >> 5;
    #pragma unroll
    for (int p = 0; p < 4; p++) {
        int k = k0 + ty + p * 8;
        t[ty + p * 8][tx] = src[(size_t)k * N + n0 + tx];
    }
    __syncthreads();
    #pragma unroll
    for (int p = 0; p < 4; p++) {
        int n = n0 + ty + p * 8;
        dst[(size_t)n * K + k0 + tx] = f2b(t[tx][ty + p * 8]);
    }
}

// ---------------- bf16 -> bf16 transpose V[t][d] -> VT[d][t] per (b,h) ----------------
__global__ __launch_bounds__(256) void v_transpose(const short* __restrict__ Vb,
                                                   short* __restrict__ VTb) {
    __shared__ short t[32][33];
    int bh = blockIdx.z;
    const short* src = Vb + (size_t)bh * TT * DHH;
    short* dst = VTb + (size_t)bh * DHH * TT;
    int t0 = blockIdx.x * 32, d0 = blockIdx.y * 32;
    int tx = threadIdx.x & 31, ty = threadIdx.x >> 5;
    #pragma unroll
    for (int p = 0; p < 4; p++)
        t[ty + p * 8][tx] = src[(size_t)(t0 + ty + p * 8) * DHH + d0 + tx];
    __syncthreads();
    #pragma unroll
    for (int p = 0; p < 4; p++)
        dst[(size_t)(d0 + ty + p * 8) * TT + t0 + tx] = t[tx][ty + p * 8];
}

// ---------------- Core bf16 MFMA GEMM loop (64x64 tile, BK=64, 4 waves) ----------------
// A: [M][K] bf16 row-major, B: [N][K] bf16 row-major.
// Staging: global_load_lds width=16, linear LDS dest, INVERSE-swizzled global source;
// reads apply slot ^ (row&7)  (rule #21: both-sides-or-neither).
__device__ __forceinline__ void gemm_loop(const short* __restrict__ A,
                                          const short* __restrict__ B,
                                          int K, short* As, short* Bs,
                                          f32x4 acc[2][2], int m0, int n0, int tid) {
    int wave = tid >> 6, lane = tid & 63;
    int wr = wave >> 1, wc = wave & 1;
    int lrow = lane & 15, lk = lane >> 4;
    int sr = tid >> 3, ss = tid & 7;
    int sswz = (ss ^ (sr & 7)) * 8;                 // swizzled 16B-slot offset (shorts)
    const short* Ag0 = A + (size_t)(m0 + sr) * K + sswz;
    const short* Ag1 = A + (size_t)(m0 + sr + 32) * K + sswz;
    const short* Bg0 = B + (size_t)(n0 + sr) * K + sswz;
    const short* Bg1 = B + (size_t)(n0 + sr + 32) * K + sswz;
    short* lA0 = As + wave * 512;                   // tid*16B linear
    short* lA1 = As + 2048 + wave * 512;
    short* lB0 = Bs + wave * 512;
    short* lB1 = Bs + 2048 + wave * 512;
    for (int k0 = 0; k0 < K; k0 += 64) {
        gload16(Ag0 + k0, lA0);
        gload16(Ag1 + k0, lA1);
        gload16(Bg0 + k0, lB0);
        gload16(Bg1 + k0, lB1);
        __syncthreads();
        #pragma unroll
        for (int kk = 0; kk < 2; kk++) {
            int slot = kk * 4 + lk;
            short8 a[2], b[2];
            #pragma unroll
            for (int i = 0; i < 2; i++) {
                int row = wr * 32 + i * 16 + lrow;
                uint4 v = ((const uint4*)As)[row * 8 + (slot ^ (row & 7))];
                a[i] = *(short8*)&v;
            }
            #pragma unroll
            for (int j = 0; j < 2; j++) {
                int row = wc * 32 + j * 16 + lrow;
                uint4 v = ((const uint4*)Bs)[row * 8 + (slot ^ (row & 7))];
                b[j] = *(short8*)&v;
            }
            #pragma unroll
            for (int i = 0; i < 2; i++)
                #pragma unroll
                for (int j = 0; j < 2; j++)
                    acc[i][j] = __builtin_amdgcn_mfma_f32_16x16x32_bf16(a[i], b[j], acc[i][j], 0, 0, 0);
        }
        __syncthreads();
    }
}

// ---------------- Generic MFMA GEMM: MODE 0: C=A@W^T+bias ; MODE 1: C=res+A@W^T+bias ----------------
template <int MODE>
__global__ __launch_bounds__(256) void gemm_mfma(const short* __restrict__ A,
                                                 const short* __restrict__ Bw,
                                                 const float* __restrict__ bias,
                                                 const float* __restrict__ res,
                                                 float* __restrict__ C,
                                                 int N, int K) {
    __shared__ short As[4096];
    __shared__ short Bs[4096];
    int tid = threadIdx.x;
    int m0 = blockIdx.y * 64, n0 = blockIdx.x * 64;
    f32x4 acc[2][2] = {};
    gemm_loop(A, Bw, K, As, Bs, acc, m0, n0, tid);
    int wave = tid >> 6, lane = tid & 63;
    int wr = wave >> 1, wc = wave & 1;
    int lrow = lane & 15, lk = lane >> 4;
    #pragma unroll
    for (int i = 0; i < 2; i++) {
        #pragma unroll
        for (int j = 0; j < 2; j++) {
            int col = n0 + wc * 32 + j * 16 + lrow;
            float bv = bias[col];
            #pragma unroll
            for (int r = 0; r < 4; r++) {
                int row = m0 + wr * 32 + i * 16 + lk * 4 + r;
                float v = acc[i][j][r] + bv;
                if (MODE == 1) v += res[(size_t)row * N + col];
                C[(size_t)row * N + col] = v;
            }
        }
    }
}

// ---------------- QKV GEMM: bf16 out, head-major split ----------------
__global__ __launch_bounds__(256) void qkv_mfma(const short* __restrict__ A,
                                                const short* __restrict__ Bw,
                                                const float* __restrict__ bias,
                                                short* __restrict__ Qb,
                                                short* __restrict__ Kb,
                                                short* __restrict__ Vb) {
    __shared__ short As[4096];
    __shared__ short Bs[4096];
    int tid = threadIdx.x;
    int m0 = blockIdx.y * 64, n0 = blockIdx.x * 64;
    f32x4 acc[2][2] = {};
    gemm_loop(A, Bw, DD, As, Bs, acc, m0, n0, tid);
    int wave = tid >> 6, lane = tid & 63;
    int wr = wave >> 1, wc = wave & 1;
    int lrow = lane & 15, lk = lane >> 4;
    int part = n0 >> 10;                 // 0:q 1:k 2:v
    int h = (n0 & 1023) >> 6;
    short* dst = (part == 0) ? Qb : ((part == 1) ? Kb : Vb);
    #pragma unroll
    for (int i = 0; i < 2; i++) {
        #pragma unroll
        for (int j = 0; j < 2; j++) {
            int d = wc * 32 + j * 16 + lrow;         // 0..63 within head
            float bv = bias[n0 + d];
            #pragma unroll
            for (int r = 0; r < 4; r++) {
                int row = m0 + wr * 32 + i * 16 + lk * 4 + r;   // token
                int b = row >> 9, t = row & (TT - 1);
                dst[(((size_t)(b * HH + h)) * TT + t) * DHH + d] = f2b(acc[i][j][r] + bv);
            }
        }
    }
}

// ---------------- scores = Q @ K^T per (b,h), f32 out ----------------
__global__ __launch_bounds__(256) void scores_mfma(const short* __restrict__ Qb,
                                                   const short* __restrict__ Kb,
                                                   float* __restrict__ S) {
    __shared__ short As[4096];
    __shared__ short Bs[4096];
    int tid = threadIdx.x;
    int bh = blockIdx.z;
    const short* A = Qb + (size_t)bh * TT * DHH;
    const short* B = Kb + (size_t)bh * TT * DHH;
    float* Sp = S + (size_t)bh * TT * TT;
    int m0 = blockIdx.y * 64, n0 = blockIdx.x * 64;
    f32x4 acc[2][2] = {};
    gemm_loop(A, B, DHH, As, Bs, acc, m0, n0, tid);
    int wave = tid >> 6, lane = tid & 63;
    int wr = wave >> 1, wc = wave & 1;
    int lrow = lane & 15, lk = lane >> 4;
    #pragma unroll
    for (int i = 0; i < 2; i++)
        #pragma unroll
        for (int j = 0; j < 2; j++) {
            int col = n0 + wc * 32 + j * 16 + lrow;
            #pragma unroll
            for (int r = 0; r < 4; r++) {
                int row = m0 + wr * 32 + i * 16 + lk * 4 + r;
                Sp[(size_t)row * TT + col] = acc[i][j][r];
            }
        }
}

// ---------------- softmax rows: P = softmax(S/8 + rel_bias), bf16 out ----------------
__global__ __launch_bounds__(256) void softmax_kernel(const float* __restrict__ S,
                                                      const float* __restrict__ rel_bias,
                                                      short* __restrict__ P) {
    int row = blockIdx.x * 4 + (threadIdx.x >> 6);   // (b*H+h)*T + t
    int lane = threadIdx.x & 63;
    int t = row & (TT - 1), h = (row >> 9) & (HH - 1);
    const float* Sr = S + (size_t)row * TT;
    const float* br = rel_bias + h * (2 * TT - 1) + (TT - 1) - t;
    float v[8];
    float mx = -1e30f;
    #pragma unroll
    for (int i = 0; i < 8; i++) {
        int s = lane + i * 64;
        v[i] = Sr[s] * 0.125f + br[s];
        mx = fmaxf(mx, v[i]);
    }
    #pragma unroll
    for (int o = 32; o; o >>= 1) mx = fmaxf(mx, __shfl_xor(mx, o));
    float sum = 0.f;
    #pragma unroll
    for (int i = 0; i < 8; i++) { v[i] = expf(v[i] - mx); sum += v[i]; }
    #pragma unroll
    for (int o = 32; o; o >>= 1) sum += __shfl_xor(sum, o);
    float inv = 1.f / sum;
    #pragma unroll
    for (int i = 0; i < 8; i++)
        P[(size_t)row * TT + lane + i * 64] = f2b(v[i] * inv);
}

// ---------------- ctx = P @ V^T per (b,h), bf16 out into [t][h*64+d] ----------------
__global__ __launch_bounds__(256) void pv_mfma(const short* __restrict__ P,
                                               const short* __restrict__ VTb,
                                               short* __restrict__ ctxb) {
    __shared__ short As[4096];
    __shared__ short Bs[4096];
    int tid = threadIdx.x;
    int bh = blockIdx.z;
    int h = bh & (HH - 1), b = bh >> 4;
    const short* A = P + (size_t)bh * TT * TT;
    const short* B = VTb + (size_t)bh * DHH * TT;
    int m0 = blockIdx.y * 64;
    f32x4 acc[2][2] = {};
    gemm_loop(A, B, TT, As, Bs, acc, m0, 0, tid);
    int wave = tid >> 6, lane = tid & 63;
    int wr = wave >> 1, wc = wave & 1;
    int lrow = lane & 15, lk = lane >> 4;
    #pragma unroll
    for (int i = 0; i < 2; i++)
        #pragma unroll
        for (int j = 0; j < 2; j++) {
            int d = wc * 32 + j * 16 + lrow;
            #pragma unroll
            for (int r = 0; r < 4; r++) {
                int row = m0 + wr * 32 + i * 16 + lk * 4 + r;   // t
                ctxb[((size_t)(b * TT + row)) * DD + h * DHH + d] = f2b(acc[i][j][r]);
            }
        }
}

// ---------------- MoE GEMM1: hid = gelu(Ag @ w1t[e]^T + b1[e]) (bf16 out) ----------------
__global__ __launch_bounds__(256) void moe_gemm1_mfma(const short* __restrict__ Ag,
                                                      const short* __restrict__ W1t,
                                                      const float* __restrict__ b1,
                                                      const int* __restrict__ counts,
                                                      const int* __restrict__ offs,
                                                      short* __restrict__ hid) {
    int e = blockIdx.y >> 4, tile = blockIdx.y & 15;
    int cnt = counts[e];
    int pcnt = (cnt + 63) & ~63;
    int row0 = tile * 64;
    if (row0 >= pcnt) return;
    int base = offs[e];
    const short* A  = Ag + (size_t)base * DD;
    const short* Bw = W1t + (size_t)e * FF * DD;   // [F][D]
    __shared__ short As[4096];
    __shared__ short Bs[4096];
    int tid = threadIdx.x;
    int n0 = blockIdx.x * 64;
    f32x4 acc[2][2] = {};
    gemm_loop(A, Bw, DD, As, Bs, acc, row0, n0, tid);
    int wave = tid >> 6, lane = tid & 63;
    int wr = wave >> 1, wc = wave & 1;
    int lrow = lane & 15, lk = lane >> 4;
    #pragma unroll
    for (int i = 0; i < 2; i++) {
        #pragma unroll
        for (int j = 0; j < 2; j++) {
            int col = n0 + wc * 32 + j * 16 + lrow;
            float bv = b1[e * FF + col];
            #pragma unroll
            for (int r = 0; r < 4; r++) {
                int row = row0 + wr * 32 + i * 16 + lk * 4 + r;
                float v = acc[i][j][r] + bv;
                float u = 0.7978845608028654f * (v + 0.044715f * v * v * v);
                float g = 0.5f * v * (1.f + tanhf(u));
                hid[(size_t)(base + row) * FF + col] = f2b(g);
            }
        }
    }
}

// ---------------- MoE GEMM2: pair_out = gate * (hid @ w2t[e]^T + b2[e]) ----------------
__global__ __launch_bounds__(256) void moe_gemm2_mfma(const short* __restrict__ hid,
                                                      const short* __restrict__ W2t,
                                                      const float* __restrict__ b2,
                                                      const float* __restrict__ pair_gate,
                                                      const int* __restrict__ counts,
                                                      const int* __restrict__ offs,
                                                      float* __restrict__ pair_out) {
    int e = blockIdx.y >> 4, tile = blockIdx.y & 15;
    int cnt = counts[e];
    int pcnt = (cnt + 63) & ~63;
    int row0 = tile * 64;
    if (row0 >= pcnt) return;
    int base = offs[e];
    const short* A  = hid + (size_t)base * FF;
    const short* Bw = W2t + (size_t)e * DD * FF;   // [D][F]
    __shared__ short As[4096];
    __shared__ short Bs[4096];
    int tid = threadIdx.x;
    int n0 = blockIdx.x * 64;
    f32x4 acc[2][2] = {};
    gemm_loop(A, Bw, FF, As, Bs, acc, row0, n0, tid);
    int wave = tid >> 6, lane = tid & 63;
    int wr = wave >> 1, wc = wave & 1;
    int lrow = lane & 15, lk = lane >> 4;
    #pragma unroll
    for (int i = 0; i < 2; i++) {
        #pragma unroll
        for (int j = 0; j < 2; j++) {
            int col = n0 + wc * 32 + j * 16 + lrow;
            float bv = b2[e * DD + col];
            #pragma unroll
            for (int r = 0; r < 4; r++) {
                int row = row0 + wr * 32 + i * 16 + lk * 4 + r;
                float g = pair_gate[base + row];
                pair_out[(size_t)(base + row) * DD + col] = g * (acc[i][j][r] + bv);
            }
        }
    }
}

// ---------------- text projection ----------------
__global__ __launch_bounds__(256) void txt_kernel(const float* __restrict__ ts,
                                                  const float* __restrict__ w,
                                                  const float* __restrict__ bias,
                                                  float* __restrict__ out) {
    int gid = blockIdx.x * 256 + threadIdx.x;   // 0..B*D-1
    int b = gid >> 10;
    int n = gid & (DD - 1);
    float acc = 0.f;
    for (int d = 0; d < DD; d++) acc += ts[b * DD + d] * w[(size_t)d * DD + n];
    out[gid] = acc + bias[n];
}

// ---------------- router ----------------
__global__ __launch_bounds__(256) void router_kernel(const float* __restrict__ h2,
                                                     const float* __restrict__ txt,
                                                     const float* __restrict__ w_r,
                                                     const float* __restrict__ b_r,
                                                     float* __restrict__ probs,
                                                     float* __restrict__ gates,
                                                     int* __restrict__ counts) {
    int row = blockIdx.x;       // token
    int b = row >> 9;
    int tid = threadIdx.x;
    float acc[EE] = {};
    for (int d = tid; d < DD; d += 256) {
        float r = h2[(size_t)row * DD + d] + txt[b * DD + d];
        #pragma unroll
        for (int e = 0; e < EE; e++) acc[e] += r * w_r[d * EE + e];
    }
    #pragma unroll
    for (int e = 0; e < EE; e++)
        #pragma unroll
        for (int o = 32; o; o >>= 1) acc[e] += __shfl_down(acc[e], o);
    __shared__ float lds[4][EE];
    int lane = tid & 63, w = tid >> 6;
    if (lane == 0)
        for (int e = 0; e < EE; e++) lds[w][e] = acc[e];
    __syncthreads();
    if (tid == 0) {
        float lg[EE], p[EE];
        float mx = -1e30f;
        for (int e = 0; e < EE; e++) {
            lg[e] = lds[0][e] + lds[1][e] + lds[2][e] + lds[3][e] + b_r[e];
            mx = fmaxf(mx, lg[e]);
        }
        float sum = 0.f;
        for (int e = 0; e < EE; e++) { p[e] = expf(lg[e] - mx); sum += p[e]; }
        float invs = 1.f / sum;
        for (int e = 0; e < EE; e++) { p[e] *= invs; probs[row * EE + e] = p[e]; }
        int i1 = 0;
        for (int e = 1; e < EE; e++) if (p[e] > p[i1]) i1 = e;
        int i2 = (i1 == 0) ? 1 : 0;
        for (int e = 0; e < EE; e++) if (e != i1 && p[e] > p[i2]) i2 = e;
        float gs = p[i1] + p[i2];
        for (int e = 0; e < EE; e++) gates[row * EE + e] = 0.f;
        gates[row * EE + i1] = p[i1] / gs;
        gates[row * EE + i2] = p[i2] / gs;
        atomicAdd(&counts[i1], 1);
        atomicAdd(&counts[i2], 1);
    }
}

// ---------------- expert offsets (64-aligned segments) ----------------
__global__ void offs_kernel(const int* __restrict__ counts, int* __restrict__ offs) {
    if (threadIdx.x == 0) {
        int acc = 0;
        for (int e = 0; e < EE; e++) { offs[e] = acc; acc += (counts[e] + 63) & ~63; }
    }
}

// ---------------- scatter tokens into per-expert lists ----------------
__global__ __launch_bounds__(256) void scatter_kernel(const float* __restrict__ gates,
                                                      const int* __restrict__ offs,
                                                      int* __restrict__ fill,
                                                      int* __restrict__ tok_pos,
                                                      float* __restrict__ pair_gate) {
    int t = blockIdx.x * 256 + threadIdx.x;   // token
    if (t >= NTOK) return;
    int slot = 0;
    for (int e = 0; e < EE; e++) {
        float g = gates[t * EE + e];
        if (g > 0.f) {
            int pos = offs[e] + atomicAdd(&fill[e], 1);
            tok_pos[t * 2 + slot] = pos;
            pair_gate[pos] = g;
            slot++;
        }
    }
}

// ---------------- gather tokens (h2 f32 -> bf16 rows of Ag) ----------------
__global__ __launch_bounds__(256) void gather_tokens(const float* __restrict__ h2,
                                                     const int* __restrict__ tok_pos,
                                                     short* __restrict__ Ag) {
    int i = blockIdx.x;          // 0..2047  (t = i>>1)
    int pos = tok_pos[i];
    int t = i >> 1;
    int d = threadIdx.x * 4;
    #pragma unroll
    for (int k = 0; k < 4; k++)
        Ag[(size_t)pos * DD + d + k] = f2b(h2[(size_t)t * DD + d + k]);
}

// ---------------- diag = mean(probs) ----------------
__global__ __launch_bounds__(256) void diag_kernel(const float* __restrict__ probs,
                                                   float* __restrict__ out) {
    int e = blockIdx.x;
    int tid = threadIdx.x;
    float s = 0.f;
    for (int t = tid; t < NTOK; t += 256) s += probs[t * EE + e];
    #pragma unroll
    for (int o = 32; o; o >>= 1) s += __shfl_down(s, o);
    __shared__ float red[4];
    if ((tid & 63) == 0) red[tid >> 6] = s;
    __syncthreads();
    if (tid == 0) out[e] = (red[0] + red[1] + red[2] + red[3]) * (1.f / NTOK);
}

// ---------------- final: out += pair_out[posA] + pair_out[posB] ----------------
__global__ __launch_bounds__(256) void finaladd_kernel(float* __restrict__ out,
                                                       const float* __restrict__ pair_out,
                                                       const int* __restrict__ tok_pos) {
    int t = blockIdx.x;
    int pA = tok_pos[2 * t], pB = tok_pos[2 * t + 1];
    int d = threadIdx.x * 4;
    float4 a = *(const float4*)&out[(size_t)t * DD + d];
    float4 u = *(const float4*)&pair_out[(size_t)pA * DD + d];
    float4 v = *(const float4*)&pair_out[(size_t)pB * DD + d];
    a.x += u.x + v.x; a.y += u.y + v.y; a.z += u.z + v.z; a.w += u.w + v.w;
    *(float4*)&out[(size_t)t * DD + d] = a;
}

extern "C" void kernel_launch(void* const* d_in, const int* in_sizes, int n_in,
                              void* d_out, int out_size, void* d_ws, size_t ws_size,
                              hipStream_t stream) {
    const float* x          = (const float*)d_in[0];
    const float* text_state = (const float*)d_in[1];
    const float* ln1_s      = (const float*)d_in[2];
    const float* ln1_b      = (const float*)d_in[3];
    const float* w_qkv      = (const float*)d_in[4];
    const float* b_qkv      = (const float*)d_in[5];
    const float* w_o        = (const float*)d_in[6];
    const float* b_o        = (const float*)d_in[7];
    const float* rel_bias   = (const float*)d_in[8];
    const float* ln2_s      = (const float*)d_in[9];
    const float* ln2_b      = (const float*)d_in[10];
    const float* w_txt      = (const float*)d_in[11];
    const float* b_txt      = (const float*)d_in[12];
    const float* w_r        = (const float*)d_in[13];
    const float* b_r        = (const float*)d_in[14];
    const float* w1         = (const float*)d_in[15];
    const float* b1         = (const float*)d_in[16];
    const float* w2         = (const float*)d_in[17];
    const float* b2         = (const float*)d_in[18];

    float* out = (float*)d_out;   // [NTOK*D] then [E] diag

    // ---- workspace layout ----
    char* p = (char*)d_ws;
    auto alloc = [&](size_t bytes) { char* r = p; p += (bytes + 255) & ~(size_t)255; return r; };
    short* h1b      = (short*)alloc((size_t)NTOK * DD * 2);
    short* Qb       = (short*)alloc((size_t)NTOK * DD * 2);
    short* Kb       = (short*)alloc((size_t)NTOK * DD * 2);
    short* Vb       = (short*)alloc((size_t)NTOK * DD * 2);
    short* VTb      = (short*)alloc((size_t)NTOK * DD * 2);
    // region1: S (f32 33.5MB) -> later Ag(5MB)+hid(20MB)
    char*  region1  = alloc((size_t)BB * HH * TT * TT * 4);
    // region2: P (bf16 16.8MB) -> later pair_out(10MB)
    char*  region2  = alloc((size_t)BB * HH * TT * TT * 2);
    short* ctxb     = (short*)alloc((size_t)NTOK * DD * 2);
    float* h2       = (float*)alloc((size_t)NTOK * DD * 4);
    float* txt      = (float*)alloc((size_t)BB * DD * 4);
    float* probs    = (float*)alloc((size_t)NTOK * EE * 4);
    float* gates    = (float*)alloc((size_t)NTOK * EE * 4);
    float* pair_gate= (float*)alloc((size_t)CAP * 4);
    int*   counts   = (int*)alloc(8 * 4);
    int*   fill     = (int*)alloc(8 * 4);
    int*   offs     = (int*)alloc(8 * 4);
    int*   tok_pos  = (int*)alloc((size_t)NTOK * 2 * 4);
    short* wqkvT    = (short*)alloc((size_t)3 * DD * DD * 2);        // [3D][D]
    short* woT      = (short*)alloc((size_t)DD * DD * 2);            // [D][D]
    short* w1T      = (short*)alloc((size_t)EE * FF * DD * 2);       // [E][F][D]
    short* w2T      = (short*)alloc((size_t)EE * DD * FF * 2);       // [E][D][F]

    float* S        = (float*)region1;
    short* P        = (short*)region2;
    short* Ag       = (short*)region1;                               // after attn
    short* hid      = (short*)(region1 + ((size_t)CAP * DD * 2 + 255 & ~(size_t)255));
    float* pair_out = (float*)region2;                               // after attn

    // ---- weight prep ----
    transpose_cast<<<dim3(3 * DD / 32, DD / 32, 1), 256, 0, stream>>>(w_qkv, wqkvT, DD, 3 * DD);
    transpose_cast<<<dim3(DD / 32, DD / 32, 1), 256, 0, stream>>>(w_o, woT, DD, DD);
    transpose_cast<<<dim3(FF / 32, DD / 32, EE), 256, 0, stream>>>(w1, w1T, DD, FF);
    transpose_cast<<<dim3(DD / 32, FF / 32, EE), 256, 0, stream>>>(w2, w2T, FF, DD);

    // ---- 1. LN1 (bf16 out) ----
    ln_kernel<1><<<NTOK, 256, 0, stream>>>(x, ln1_s, ln1_b, h1b);
    // ---- 2. QKV GEMM -> bf16 head-major Q/K/V ----
    qkv_mfma<<<dim3(3 * DD / 64, NTOK / 64), 256, 0, stream>>>(h1b, wqkvT, b_qkv, Qb, Kb, Vb);
    // ---- 3. V transpose per (b,h) ----
    v_transpose<<<dim3(TT / 32, DHH / 32, BB * HH), 256, 0, stream>>>(Vb, VTb);
    // ---- 4. scores ----
    scores_mfma<<<dim3(TT / 64, TT / 64, BB * HH), 256, 0, stream>>>(Qb, Kb, S);
    // ---- 5. softmax (scale + rel bias folded) ----
    softmax_kernel<<<BB * HH * TT / 4, 256, 0, stream>>>(S, rel_bias, P);
    // ---- 6. ctx = P @ V^T ----
    pv_mfma<<<dim3(1, TT / 64, BB * HH), 256, 0, stream>>>(P, VTb, ctxb);
    // ---- 7. x1 = x + ctx @ w_o + b_o -> out ----
    gemm_mfma<1><<<dim3(DD / 64, NTOK / 64), 256, 0, stream>>>(ctxb, woT, b_o, x, out, DD, DD);
    // ---- 8. LN2 (f32 out) ----
    ln_kernel<0><<<NTOK, 256, 0, stream>>>(out, ln2_s, ln2_b, h2);
    // ---- 9. text projection ----
    txt_kernel<<<(BB * DD) / 256, 256, 0, stream>>>(text_state, w_txt, b_txt, txt);
    // ---- 10. zero scratch ----
    hipMemsetAsync(counts, 0, 8 * 4, stream);
    hipMemsetAsync(fill, 0, 8 * 4, stream);
    hipMemsetAsync(Ag, 0, (size_t)CAP * DD * 2, stream);
    // ---- 11. router ----
    router_kernel<<<NTOK, 256, 0, stream>>>(h2, txt, w_r, b_r, probs, gates, counts);
    // ---- 12. aligned offsets ----
    offs_kernel<<<1, 64, 0, stream>>>(counts, offs);
    // ---- 13. scatter ----
    scatter_kernel<<<NTOK / 256, 256, 0, stream>>>(gates, offs, fill, tok_pos, pair_gate);
    // ---- 14. gather rows into Ag (bf16) ----
    gather_tokens<<<NTOK * 2, 256, 0, stream>>>(h2, tok_pos, Ag);
    // ---- 15. diag ----
    diag_kernel<<<EE, 256, 0, stream>>>(probs, out + (size_t)NTOK * DD);
    // ---- 16. MoE GEMM1 ----
    moe_gemm1_mfma<<<dim3(FF / 64, EE * 16), 256, 0, stream>>>(Ag, w1T, b1, counts, offs, hid);
    // ---- 17. MoE GEMM2 ----
    moe_gemm2_mfma<<<dim3(DD / 64, EE * 16), 256, 0, stream>>>(hid, w2T, b2, pair_gate, counts, offs, pair_out);
    // ---- 18. final add ----
    finaladd_kernel<<<NTOK, 256, 0, stream>>>(out, pair_out, tok_pos);
}